// Round 5
// baseline (130.512 us; speedup 1.0000x reference)
//
#include <hip/hip_runtime.h>

// CostVolume: x,y fp32 [2,64,96,320]; GROUP=8 -> 8 groups x 8 channels.
// Per group: L2-normalize the 8-channel vector per pixel (+EPS on norm),
// cost[b,g,d,h,j] = sum_cc | xn[cc][h][j] - yn[cc][h][j-d] |, yn term = 0
// when j < d (left zero-pad -> cost = sum|xn|). Output [2,8,49,96,320] fp32.
//
// v6 = v5 + non-temporal packed stores.
// v5 fixed the write-scatter wall (d-plane lockstep sweep: one block per CU,
// 256 blocks = 16 bg x 16 h-bands, 960 thr = 6 rows x 160 col-pairs; chip
// writes the full out[:,d,:,:] plane per step as 16 quasi-sequential
// streams). Kernel is now write-bound near the 15.3us floor (96.3MB @
// 6.3TB/s). The output is write-once/never-read: route stores around L2
// with the nt bit (__builtin_nontemporal_store on a packed u64) so the
// write-back cache neither reorders the stream nor evicts x/y lines.
// Inner math identical: x in regs, y normalized once into LDS
// (parity-split, 60KB), sliding-window reuse (1 fresh ds_read_b128 pair
// per step covers 2 output pixels), float2 global loads.

#define MAXDISP 48
#define NDISP   49
#define HH      96
#define WW      320
#define HW      (HH * WW)      // 30720
#define EPSN    1e-5f
#define GROWS   6              // h rows per block; 96/6 = 16 bands

__global__ __launch_bounds__(960, 4) void cost_volume_kernel(
    const float* __restrict__ x, const float* __restrict__ y,
    float* __restrict__ out)
{
    // [row][parity][half][idx]: 6*2*2*160*16B = 61,440 B
    __shared__ float4 ylds[GROWS][2][2][WW / 2];

    const int tid = threadIdx.x;
    const int q   = tid % 160;          // column-pair index
    const int r   = tid / 160;          // row within band, 0..5
    const int j   = 2 * q;

    const int blk = blockIdx.x;         // 0..255
    const int hb  = blk % 16;           // h-band
    const int bg  = blk / 16;           // b*8+g
    const int h   = hb * GROWS + r;

    const int inBase = bg * 8 * HW + h * WW + j;

    float xa[8], xb[8];                 // a = col j, b = col j+1
    float xsa = 0.f, xsb = 0.f;
#pragma unroll
    for (int cc = 0; cc < 8; ++cc) {
        const float2 xi = *reinterpret_cast<const float2*>(x + inBase + cc * HW);
        xa[cc] = xi.x; xb[cc] = xi.y;
        xsa += xi.x * xi.x; xsb += xi.y * xi.y;
    }
    const float xia = 1.f / (sqrtf(xsa) + EPSN);
    const float xib = 1.f / (sqrtf(xsb) + EPSN);
    float sAbsA = 0.f, sAbsB = 0.f;
#pragma unroll
    for (int cc = 0; cc < 8; ++cc) {
        xa[cc] *= xia; xb[cc] *= xib;
        sAbsA += fabsf(xa[cc]);
        sAbsB += fabsf(xb[cc]);
    }

    {   // stage this row's y (each thread loads its own 2 columns)
        float ya[8], yb[8];
        float ysa = 0.f, ysb = 0.f;
#pragma unroll
        for (int cc = 0; cc < 8; ++cc) {
            const float2 yi = *reinterpret_cast<const float2*>(y + inBase + cc * HW);
            ya[cc] = yi.x; yb[cc] = yi.y;
            ysa += yi.x * yi.x; ysb += yi.y * yi.y;
        }
        const float yia = 1.f / (sqrtf(ysa) + EPSN);
        const float yib = 1.f / (sqrtf(ysb) + EPSN);
#pragma unroll
        for (int cc = 0; cc < 8; ++cc) { ya[cc] *= yia; yb[cc] *= yib; }
        ylds[r][0][0][q] = make_float4(ya[0], ya[1], ya[2], ya[3]);
        ylds[r][0][1][q] = make_float4(ya[4], ya[5], ya[6], ya[7]);
        ylds[r][1][0][q] = make_float4(yb[0], yb[1], yb[2], yb[3]);
        ylds[r][1][1][q] = make_float4(yb[4], yb[5], yb[6], yb[7]);
    }
    __syncthreads();

    const float4* const ldsE = &ylds[r][0][0][0];   // even cols, [2][160]
    const float4* const ldsO = &ylds[r][1][0][0];   // odd  cols, [2][160]

    // initial window at d=0: yp = Y(j), yc = Y(j+1)
    float4 yp0 = ldsE[q], yp1 = ldsE[160 + q];
    float4 yc0 = ldsO[q], yc1 = ldsO[160 + q];

    float* const outBase = out + bg * (NDISP * HW) + h * WW + j;

    // One step at disparity D; fresh read (next iteration's yp = Y(j-D-1))
    // comes from FB (ldsO when D even, ldsE when D odd).
#define CV_STEP(D, FB, DO_FRESH)                                            \
    {                                                                       \
        float c0 = fabsf(xa[0] - yp0.x) + fabsf(xa[1] - yp0.y)              \
                 + fabsf(xa[2] - yp0.z) + fabsf(xa[3] - yp0.w)              \
                 + fabsf(xa[4] - yp1.x) + fabsf(xa[5] - yp1.y)              \
                 + fabsf(xa[6] - yp1.z) + fabsf(xa[7] - yp1.w);             \
        float c1 = fabsf(xb[0] - yc0.x) + fabsf(xb[1] - yc0.y)              \
                 + fabsf(xb[2] - yc0.z) + fabsf(xb[3] - yc0.w)              \
                 + fabsf(xb[4] - yc1.x) + fabsf(xb[5] - yc1.y)              \
                 + fabsf(xb[6] - yc1.z) + fabsf(xb[7] - yc1.w);             \
        c0 = ((D) <= j)     ? c0 : sAbsA;                                   \
        c1 = ((D) <= j + 1) ? c1 : sAbsB;                                   \
        union { float2 f2; unsigned long long u; } pk_;                     \
        pk_.f2 = make_float2(c0, c1);                                       \
        __builtin_nontemporal_store(pk_.u,                                  \
            reinterpret_cast<unsigned long long*>(outBase + (D) * HW));     \
        yc0 = yp0; yc1 = yp1;                                               \
        if (DO_FRESH) {                                                     \
            const int pn = j - (D) - 1;                                     \
            const int ix = (pn > 0 ? pn : 0) >> 1;                          \
            yp0 = (FB)[ix]; yp1 = (FB)[160 + ix];                           \
        }                                                                   \
    }

#pragma unroll
    for (int ii = 0; ii < 24; ++ii) {
        const int d0 = 2 * ii;
        CV_STEP(d0,     ldsO, 1);   // d even: fresh position odd
        CV_STEP(d0 + 1, ldsE, 1);   // d odd : fresh position even
    }
    CV_STEP(MAXDISP, ldsO, 0);      // d = 48, no fresh read

#undef CV_STEP
}

extern "C" void kernel_launch(void* const* d_in, const int* in_sizes, int n_in,
                              void* d_out, int out_size, void* d_ws, size_t ws_size,
                              hipStream_t stream) {
    const float* x = (const float*)d_in[0];
    const float* y = (const float*)d_in[1];
    float* out = (float*)d_out;
    // grid = 16 bg x 16 h-bands = 256 blocks (1 per CU), 960 threads (15 waves)
    dim3 grid(16 * (HH / GROWS));
    dim3 block(GROWS * (WW / 2));
    cost_volume_kernel<<<grid, block, 0, stream>>>(x, y, out);
}

// Round 6
// 125.242 us; speedup vs baseline: 1.0421x; 1.0421x over previous
//
#include <hip/hip_runtime.h>

// CostVolume: x,y fp32 [2,64,96,320]; GROUP=8 -> 8 groups x 8 channels.
// Per group: L2-normalize the 8-channel vector per pixel (+EPS on norm),
// cost[b,g,d,h,j] = sum_cc | xn[cc][h][j] - yn[cc][h][j-d] |, yn term = 0
// when j < d (left zero-pad -> cost = sum|xn|). Output [2,8,49,96,320] fp32.
//
// v7 = v5 (revert of v6's non-temporal stores, which regressed +6us:
// the nt bit bypasses L2 write-combining, and L2 aggregation of the 16
// interleaved 7.5KB strips IS what makes the write stream fast here).
//
// Structure (best measured: 124.4us total, kernel ~10us):
// one block per CU (grid 256 = 16 bg x 16 h-bands), 960 thr = 6 rows x
// 160 col-pairs. All blocks sweep d in lockstep; per d-step each block
// writes 7.5KB contiguous and the chip writes the full 1.9MB out[:,d,:,:]
// plane in ascending d => 16 quasi-sequential write streams, L2-combined.
// x in regs, y normalized once into LDS (parity-split, 60KB),
// sliding-window reuse (1 fresh ds_read_b128 pair per step covers 2
// output pixels), float2 global loads/stores.

#define MAXDISP 48
#define NDISP   49
#define HH      96
#define WW      320
#define HW      (HH * WW)      // 30720
#define EPSN    1e-5f
#define GROWS   6              // h rows per block; 96/6 = 16 bands

__global__ __launch_bounds__(960, 4) void cost_volume_kernel(
    const float* __restrict__ x, const float* __restrict__ y,
    float* __restrict__ out)
{
    // [row][parity][half][idx]: 6*2*2*160*16B = 61,440 B
    __shared__ float4 ylds[GROWS][2][2][WW / 2];

    const int tid = threadIdx.x;
    const int q   = tid % 160;          // column-pair index
    const int r   = tid / 160;          // row within band, 0..5
    const int j   = 2 * q;

    const int blk = blockIdx.x;         // 0..255
    const int hb  = blk % 16;           // h-band
    const int bg  = blk / 16;           // b*8+g
    const int h   = hb * GROWS + r;

    const int inBase = bg * 8 * HW + h * WW + j;

    float xa[8], xb[8];                 // a = col j, b = col j+1
    float xsa = 0.f, xsb = 0.f;
#pragma unroll
    for (int cc = 0; cc < 8; ++cc) {
        const float2 xi = *reinterpret_cast<const float2*>(x + inBase + cc * HW);
        xa[cc] = xi.x; xb[cc] = xi.y;
        xsa += xi.x * xi.x; xsb += xi.y * xi.y;
    }
    const float xia = 1.f / (sqrtf(xsa) + EPSN);
    const float xib = 1.f / (sqrtf(xsb) + EPSN);
    float sAbsA = 0.f, sAbsB = 0.f;
#pragma unroll
    for (int cc = 0; cc < 8; ++cc) {
        xa[cc] *= xia; xb[cc] *= xib;
        sAbsA += fabsf(xa[cc]);
        sAbsB += fabsf(xb[cc]);
    }

    {   // stage this row's y (each thread loads its own 2 columns)
        float ya[8], yb[8];
        float ysa = 0.f, ysb = 0.f;
#pragma unroll
        for (int cc = 0; cc < 8; ++cc) {
            const float2 yi = *reinterpret_cast<const float2*>(y + inBase + cc * HW);
            ya[cc] = yi.x; yb[cc] = yi.y;
            ysa += yi.x * yi.x; ysb += yi.y * yi.y;
        }
        const float yia = 1.f / (sqrtf(ysa) + EPSN);
        const float yib = 1.f / (sqrtf(ysb) + EPSN);
#pragma unroll
        for (int cc = 0; cc < 8; ++cc) { ya[cc] *= yia; yb[cc] *= yib; }
        ylds[r][0][0][q] = make_float4(ya[0], ya[1], ya[2], ya[3]);
        ylds[r][0][1][q] = make_float4(ya[4], ya[5], ya[6], ya[7]);
        ylds[r][1][0][q] = make_float4(yb[0], yb[1], yb[2], yb[3]);
        ylds[r][1][1][q] = make_float4(yb[4], yb[5], yb[6], yb[7]);
    }
    __syncthreads();

    const float4* const ldsE = &ylds[r][0][0][0];   // even cols, [2][160]
    const float4* const ldsO = &ylds[r][1][0][0];   // odd  cols, [2][160]

    // initial window at d=0: yp = Y(j), yc = Y(j+1)
    float4 yp0 = ldsE[q], yp1 = ldsE[160 + q];
    float4 yc0 = ldsO[q], yc1 = ldsO[160 + q];

    float* const outBase = out + bg * (NDISP * HW) + h * WW + j;

    // One step at disparity D; fresh read (next iteration's yp = Y(j-D-1))
    // comes from FB (ldsO when D even, ldsE when D odd).
#define CV_STEP(D, FB, DO_FRESH)                                            \
    {                                                                       \
        float c0 = fabsf(xa[0] - yp0.x) + fabsf(xa[1] - yp0.y)              \
                 + fabsf(xa[2] - yp0.z) + fabsf(xa[3] - yp0.w)              \
                 + fabsf(xa[4] - yp1.x) + fabsf(xa[5] - yp1.y)              \
                 + fabsf(xa[6] - yp1.z) + fabsf(xa[7] - yp1.w);             \
        float c1 = fabsf(xb[0] - yc0.x) + fabsf(xb[1] - yc0.y)              \
                 + fabsf(xb[2] - yc0.z) + fabsf(xb[3] - yc0.w)              \
                 + fabsf(xb[4] - yc1.x) + fabsf(xb[5] - yc1.y)              \
                 + fabsf(xb[6] - yc1.z) + fabsf(xb[7] - yc1.w);             \
        c0 = ((D) <= j)     ? c0 : sAbsA;                                   \
        c1 = ((D) <= j + 1) ? c1 : sAbsB;                                   \
        *reinterpret_cast<float2*>(outBase + (D) * HW) = make_float2(c0, c1);\
        yc0 = yp0; yc1 = yp1;                                               \
        if (DO_FRESH) {                                                     \
            const int pn = j - (D) - 1;                                     \
            const int ix = (pn > 0 ? pn : 0) >> 1;                          \
            yp0 = (FB)[ix]; yp1 = (FB)[160 + ix];                           \
        }                                                                   \
    }

#pragma unroll
    for (int ii = 0; ii < 24; ++ii) {
        const int d0 = 2 * ii;
        CV_STEP(d0,     ldsO, 1);   // d even: fresh position odd
        CV_STEP(d0 + 1, ldsE, 1);   // d odd : fresh position even
    }
    CV_STEP(MAXDISP, ldsO, 0);      // d = 48, no fresh read

#undef CV_STEP
}

extern "C" void kernel_launch(void* const* d_in, const int* in_sizes, int n_in,
                              void* d_out, int out_size, void* d_ws, size_t ws_size,
                              hipStream_t stream) {
    const float* x = (const float*)d_in[0];
    const float* y = (const float*)d_in[1];
    float* out = (float*)d_out;
    // grid = 16 bg x 16 h-bands = 256 blocks (1 per CU), 960 threads (15 waves)
    dim3 grid(16 * (HH / GROWS));
    dim3 block(GROWS * (WW / 2));
    cost_volume_kernel<<<grid, block, 0, stream>>>(x, y, out);
}

// Round 7
// 123.235 us; speedup vs baseline: 1.0591x; 1.0163x over previous
//
#include <hip/hip_runtime.h>

// CostVolume: x,y fp32 [2,64,96,320]; GROUP=8 -> 8 groups x 8 channels.
// Per group: L2-normalize the 8-channel vector per pixel (+EPS on norm),
// cost[b,g,d,h,j] = sum_cc | xn[cc][h][j] - yn[cc][h][j-d] |, yn term = 0
// when j < d (left zero-pad -> cost = sum|xn|). Output [2,8,49,96,320] fp32.
//
// v8 = v5/v7 with the register contract relaxed.
// v7's counters showed VGPR_Count=32: __launch_bounds__(960,4) made the
// allocator budget for 2 co-resident 15-wave blocks and squeeze the ~56-reg
// live set into 32 -> the yp/yc sliding window got demoted to redundant LDS
// re-reads + serialized chains (rocprof kernel 69us, VALUBusy 20%, no
// scratch traffic = demotion not spilling). Grid is exactly 1 block/CU, so
// that frugality buys nothing. (960,2) raises the cap so the window and x
// vectors actually live in registers as designed.
//
// Structure (best measured: 124.4us total):
// one block per CU (grid 256 = 16 bg x 16 h-bands), 960 thr = 6 rows x
// 160 col-pairs. All blocks sweep d in lockstep; per d-step each block
// writes 7.5KB contiguous and the chip writes the full 1.9MB out[:,d,:,:]
// plane in ascending d => 16 quasi-sequential write streams, L2-combined
// (v6 showed nt stores that bypass L2 combining cost +6us).
// x in regs, y normalized once into LDS (parity-split, 60KB),
// sliding-window reuse (1 fresh ds_read_b128 pair per step covers 2
// output pixels), float2 global loads/stores.

#define MAXDISP 48
#define NDISP   49
#define HH      96
#define WW      320
#define HW      (HH * WW)      // 30720
#define EPSN    1e-5f
#define GROWS   6              // h rows per block; 96/6 = 16 bands

__global__ __launch_bounds__(960, 2) void cost_volume_kernel(
    const float* __restrict__ x, const float* __restrict__ y,
    float* __restrict__ out)
{
    // [row][parity][half][idx]: 6*2*2*160*16B = 61,440 B
    __shared__ float4 ylds[GROWS][2][2][WW / 2];

    const int tid = threadIdx.x;
    const int q   = tid % 160;          // column-pair index
    const int r   = tid / 160;          // row within band, 0..5
    const int j   = 2 * q;

    const int blk = blockIdx.x;         // 0..255
    const int hb  = blk % 16;           // h-band
    const int bg  = blk / 16;           // b*8+g
    const int h   = hb * GROWS + r;

    const int inBase = bg * 8 * HW + h * WW + j;

    float xa[8], xb[8];                 // a = col j, b = col j+1
    float xsa = 0.f, xsb = 0.f;
#pragma unroll
    for (int cc = 0; cc < 8; ++cc) {
        const float2 xi = *reinterpret_cast<const float2*>(x + inBase + cc * HW);
        xa[cc] = xi.x; xb[cc] = xi.y;
        xsa += xi.x * xi.x; xsb += xi.y * xi.y;
    }
    const float xia = 1.f / (sqrtf(xsa) + EPSN);
    const float xib = 1.f / (sqrtf(xsb) + EPSN);
    float sAbsA = 0.f, sAbsB = 0.f;
#pragma unroll
    for (int cc = 0; cc < 8; ++cc) {
        xa[cc] *= xia; xb[cc] *= xib;
        sAbsA += fabsf(xa[cc]);
        sAbsB += fabsf(xb[cc]);
    }

    {   // stage this row's y (each thread loads its own 2 columns)
        float ya[8], yb[8];
        float ysa = 0.f, ysb = 0.f;
#pragma unroll
        for (int cc = 0; cc < 8; ++cc) {
            const float2 yi = *reinterpret_cast<const float2*>(y + inBase + cc * HW);
            ya[cc] = yi.x; yb[cc] = yi.y;
            ysa += yi.x * yi.x; ysb += yi.y * yi.y;
        }
        const float yia = 1.f / (sqrtf(ysa) + EPSN);
        const float yib = 1.f / (sqrtf(ysb) + EPSN);
#pragma unroll
        for (int cc = 0; cc < 8; ++cc) { ya[cc] *= yia; yb[cc] *= yib; }
        ylds[r][0][0][q] = make_float4(ya[0], ya[1], ya[2], ya[3]);
        ylds[r][0][1][q] = make_float4(ya[4], ya[5], ya[6], ya[7]);
        ylds[r][1][0][q] = make_float4(yb[0], yb[1], yb[2], yb[3]);
        ylds[r][1][1][q] = make_float4(yb[4], yb[5], yb[6], yb[7]);
    }
    __syncthreads();

    const float4* const ldsE = &ylds[r][0][0][0];   // even cols, [2][160]
    const float4* const ldsO = &ylds[r][1][0][0];   // odd  cols, [2][160]

    // initial window at d=0: yp = Y(j), yc = Y(j+1)
    float4 yp0 = ldsE[q], yp1 = ldsE[160 + q];
    float4 yc0 = ldsO[q], yc1 = ldsO[160 + q];

    float* const outBase = out + bg * (NDISP * HW) + h * WW + j;

    // One step at disparity D; fresh read (next iteration's yp = Y(j-D-1))
    // comes from FB (ldsO when D even, ldsE when D odd).
#define CV_STEP(D, FB, DO_FRESH)                                            \
    {                                                                       \
        float c0 = fabsf(xa[0] - yp0.x) + fabsf(xa[1] - yp0.y)              \
                 + fabsf(xa[2] - yp0.z) + fabsf(xa[3] - yp0.w)              \
                 + fabsf(xa[4] - yp1.x) + fabsf(xa[5] - yp1.y)              \
                 + fabsf(xa[6] - yp1.z) + fabsf(xa[7] - yp1.w);             \
        float c1 = fabsf(xb[0] - yc0.x) + fabsf(xb[1] - yc0.y)              \
                 + fabsf(xb[2] - yc0.z) + fabsf(xb[3] - yc0.w)              \
                 + fabsf(xb[4] - yc1.x) + fabsf(xb[5] - yc1.y)              \
                 + fabsf(xb[6] - yc1.z) + fabsf(xb[7] - yc1.w);             \
        c0 = ((D) <= j)     ? c0 : sAbsA;                                   \
        c1 = ((D) <= j + 1) ? c1 : sAbsB;                                   \
        *reinterpret_cast<float2*>(outBase + (D) * HW) = make_float2(c0, c1);\
        yc0 = yp0; yc1 = yp1;                                               \
        if (DO_FRESH) {                                                     \
            const int pn = j - (D) - 1;                                     \
            const int ix = (pn > 0 ? pn : 0) >> 1;                          \
            yp0 = (FB)[ix]; yp1 = (FB)[160 + ix];                           \
        }                                                                   \
    }

#pragma unroll
    for (int ii = 0; ii < 24; ++ii) {
        const int d0 = 2 * ii;
        CV_STEP(d0,     ldsO, 1);   // d even: fresh position odd
        CV_STEP(d0 + 1, ldsE, 1);   // d odd : fresh position even
    }
    CV_STEP(MAXDISP, ldsO, 0);      // d = 48, no fresh read

#undef CV_STEP
}

extern "C" void kernel_launch(void* const* d_in, const int* in_sizes, int n_in,
                              void* d_out, int out_size, void* d_ws, size_t ws_size,
                              hipStream_t stream) {
    const float* x = (const float*)d_in[0];
    const float* y = (const float*)d_in[1];
    float* out = (float*)d_out;
    // grid = 16 bg x 16 h-bands = 256 blocks (1 per CU), 960 threads (15 waves)
    dim3 grid(16 * (HH / GROWS));
    dim3 block(GROWS * (WW / 2));
    cost_volume_kernel<<<grid, block, 0, stream>>>(x, y, out);
}